// Round 4
// baseline (904.136 us; speedup 1.0000x reference)
//
#include <hip/hip_runtime.h>

#define FIN 256
#define FH  64
#define SCAN_BLK 1024

// ---------------- degree / normalization ----------------

__global__ __launch_bounds__(256) void deg_kernel(const int* __restrict__ rows,
                                                  unsigned* __restrict__ deg, int E) {
    int e = blockIdx.x * 256 + threadIdx.x;
    if (e < E) atomicAdd(&deg[rows[e]], 1u);
}

__global__ __launch_bounds__(256) void dis_kernel(const unsigned* __restrict__ deg,
                                                  float* __restrict__ dis, int N) {
    int i = blockIdx.x * 256 + threadIdx.x;
    if (i < N) {
        unsigned d = deg[i];
        dis[i] = d ? 1.0f / sqrtf((float)d) : 0.0f;
    }
}

// ---------------- exclusive scan of deg -> rowptr (3 kernels) ----------------

__global__ __launch_bounds__(256) void scan_block_kernel(const unsigned* __restrict__ deg,
                                                         int* __restrict__ rowptr,
                                                         int* __restrict__ blocksums, int N) {
    __shared__ int wsum[4];
    const int t = threadIdx.x;
    const int base = blockIdx.x * SCAN_BLK + t * 4;
    int d0 = 0, d1 = 0, d2 = 0, d3 = 0;
    if (base + 0 < N) d0 = (int)deg[base + 0];
    if (base + 1 < N) d1 = (int)deg[base + 1];
    if (base + 2 < N) d2 = (int)deg[base + 2];
    if (base + 3 < N) d3 = (int)deg[base + 3];
    const int tot = d0 + d1 + d2 + d3;
    const int lane = t & 63, wv = t >> 6;
    int inc = tot;
#pragma unroll
    for (int off = 1; off < 64; off <<= 1) {
        int v = __shfl_up(inc, off, 64);
        if (lane >= off) inc += v;
    }
    if (lane == 63) wsum[wv] = inc;
    __syncthreads();
    int woff = 0;
    for (int w = 0; w < wv; ++w) woff += wsum[w];
    const int ex = woff + inc - tot;   // exclusive prefix of this thread within block
    if (base + 0 < N) rowptr[base + 0] = ex;
    if (base + 1 < N) rowptr[base + 1] = ex + d0;
    if (base + 2 < N) rowptr[base + 2] = ex + d0 + d1;
    if (base + 3 < N) rowptr[base + 3] = ex + d0 + d1 + d2;
    if (t == 255) blocksums[blockIdx.x] = woff + inc;   // block total
}

__global__ void scan_sums_kernel(int* __restrict__ blocksums, int nb) {
    if (threadIdx.x == 0 && blockIdx.x == 0) {
        int run = 0;
        for (int i = 0; i < nb; ++i) { int v = blocksums[i]; blocksums[i] = run; run += v; }
    }
}

__global__ __launch_bounds__(256) void scan_add_kernel(int* __restrict__ rowptr,
                                                       int* __restrict__ cursor,
                                                       const int* __restrict__ blocksums,
                                                       int N, int E) {
    int i = blockIdx.x * 256 + threadIdx.x;
    if (i < N) {
        int v = rowptr[i] + blocksums[i / SCAN_BLK];
        rowptr[i] = v;
        cursor[i] = v;
    }
    if (i == 0) rowptr[N] = E;
}

// ---------------- counting-sort edges into CSR col + edge-id arrays ----------------

__global__ __launch_bounds__(256) void scatter_edges_kernel(const int* __restrict__ rows,
                                                            const int* __restrict__ cols,
                                                            int* __restrict__ cursor,
                                                            int* __restrict__ colOut,
                                                            int* __restrict__ eidOut,
                                                            int idofs, int E) {
    int e = blockIdx.x * 256 + threadIdx.x;
    if (e < E) {
        int p = atomicAdd(&cursor[rows[e]], 1);
        colOut[p] = cols[e];
        eidOut[p] = e + idofs;
    }
}

// ---------------- GEMM1: out[N][64] = (x[N][256] @ W[256][64] + b) * dis[r] ----------------

__global__ __launch_bounds__(256) void gemm1_kernel(const float* __restrict__ x,
                                                    const float* __restrict__ W,
                                                    const float* __restrict__ b,
                                                    const float* __restrict__ dis,
                                                    float* __restrict__ out, int N) {
    __shared__ float xs[32][260];
    __shared__ float ws[32][64];
    const int t = threadIdx.x;
    const int rb = blockIdx.x * 256;
    const int rg = t >> 3, cg = t & 7;
    const int r0 = rg * 8, c0 = cg * 8;
    float acc[8][8];
#pragma unroll
    for (int i = 0; i < 8; ++i)
#pragma unroll
        for (int j = 0; j < 8; ++j) acc[i][j] = 0.f;

    const float4* x4 = (const float4*)x;
    const int kk = (t & 7) * 4;
    const int rloc = t >> 3;

    for (int k0 = 0; k0 < FIN; k0 += 32) {
        __syncthreads();
        {
            const float4* w4 = (const float4*)(W + k0 * 64);
            float4* wl = (float4*)&ws[0][0];
            wl[t]       = w4[t];
            wl[t + 256] = w4[t + 256];
        }
#pragma unroll
        for (int p = 0; p < 8; ++p) {
            int r = rloc + p * 32;
            int gr = rb + r; if (gr >= N) gr = N - 1;
            float4 v = x4[gr * 64 + (k0 >> 2) + (t & 7)];
            xs[kk + 0][r] = v.x; xs[kk + 1][r] = v.y;
            xs[kk + 2][r] = v.z; xs[kk + 3][r] = v.w;
        }
        __syncthreads();
#pragma unroll
        for (int k = 0; k < 32; ++k) {
            float4 xa = *(const float4*)&xs[k][r0];
            float4 xb = *(const float4*)&xs[k][r0 + 4];
            float4 wa = *(const float4*)&ws[k][c0];
            float4 wb = *(const float4*)&ws[k][c0 + 4];
            float xr[8] = {xa.x, xa.y, xa.z, xa.w, xb.x, xb.y, xb.z, xb.w};
            float wr[8] = {wa.x, wa.y, wa.z, wa.w, wb.x, wb.y, wb.z, wb.w};
#pragma unroll
            for (int i = 0; i < 8; ++i)
#pragma unroll
                for (int j = 0; j < 8; ++j) acc[i][j] = fmaf(xr[i], wr[j], acc[i][j]);
        }
    }
    float bias[8];
#pragma unroll
    for (int j = 0; j < 8; ++j) bias[j] = b[c0 + j];
#pragma unroll
    for (int i = 0; i < 8; ++i) {
        int gr = rb + r0 + i;
        if (gr < N) {
            float d = dis[gr];
            float4 o0, o1;
            o0.x = (acc[i][0] + bias[0]) * d; o0.y = (acc[i][1] + bias[1]) * d;
            o0.z = (acc[i][2] + bias[2]) * d; o0.w = (acc[i][3] + bias[3]) * d;
            o1.x = (acc[i][4] + bias[4]) * d; o1.y = (acc[i][5] + bias[5]) * d;
            o1.z = (acc[i][6] + bias[6]) * d; o1.w = (acc[i][7] + bias[7]) * d;
            *(float4*)&out[gr * 64 + c0]     = o0;
            *(float4*)&out[gr * 64 + c0 + 4] = o1;
        }
    }
}

// ---------------- CSR gather aggregation: out[r] = sum over neighbors of h[c] ----------------

__global__ __launch_bounds__(256) void gather_agg_kernel(const int* __restrict__ rowptr,
                                                         const int* __restrict__ cols,
                                                         const float* __restrict__ h,
                                                         float* __restrict__ out, int N) {
    int r = blockIdx.x * 4 + (threadIdx.x >> 6);
    int lane = threadIdx.x & 63;
    if (r >= N) return;
    int s = rowptr[r], e = rowptr[r + 1];
    float acc0 = 0.f, acc1 = 0.f;
    for (int base = s; base < e; base += 64) {
        int n = e - base; if (n > 64) n = 64;
        int idx = (lane < n) ? cols[base + lane] : 0;
        int j = 0;
        for (; j + 1 < n; j += 2) {
            int c0 = __shfl(idx, j, 64);
            int c1 = __shfl(idx, j + 1, 64);
            acc0 += h[(size_t)c0 * 64 + lane];
            acc1 += h[(size_t)c1 * 64 + lane];
        }
        if (j < n) {
            int c0 = __shfl(idx, j, 64);
            acc0 += h[(size_t)c0 * 64 + lane];
        }
    }
    out[(size_t)r * 64 + lane] = acc0 + acc1;
}

// ---------------- GEMM2: out[N][64] = (relu(dis[r]*agg[r]) @ W[64][64] + b) * dis[r] ----------------

__global__ __launch_bounds__(256) void gemm2_kernel(const float* __restrict__ agg,
                                                    const float* __restrict__ dis,
                                                    const float* __restrict__ W,
                                                    const float* __restrict__ b,
                                                    float* __restrict__ out, int N) {
    __shared__ float xs[64][132];
    __shared__ float ws[64][64];
    const int t = threadIdx.x;
    const int rb = blockIdx.x * 128;
    {
        const float4* w4 = (const float4*)W;
        float4* wl = (float4*)&ws[0][0];
#pragma unroll
        for (int p = 0; p < 4; ++p) wl[p * 256 + t] = w4[p * 256 + t];
    }
    {
        const float4* a4 = (const float4*)agg;
        const int c4 = (t & 15) * 4;
        const int rloc = t >> 4;
#pragma unroll
        for (int p = 0; p < 8; ++p) {
            int r = rloc + p * 16;
            int gr = rb + r; if (gr >= N) gr = N - 1;
            float d = dis[gr];
            float4 v = a4[gr * 16 + (t & 15)];
            xs[c4 + 0][r] = fmaxf(v.x * d, 0.f);
            xs[c4 + 1][r] = fmaxf(v.y * d, 0.f);
            xs[c4 + 2][r] = fmaxf(v.z * d, 0.f);
            xs[c4 + 3][r] = fmaxf(v.w * d, 0.f);
        }
    }
    __syncthreads();
    const int rg = t >> 3, cg = t & 7;
    const int r0 = rg * 4, c0 = cg * 8;
    float acc[4][8];
#pragma unroll
    for (int i = 0; i < 4; ++i)
#pragma unroll
        for (int j = 0; j < 8; ++j) acc[i][j] = 0.f;
#pragma unroll 16
    for (int k = 0; k < 64; ++k) {
        float4 xa = *(const float4*)&xs[k][r0];
        float4 wa = *(const float4*)&ws[k][c0];
        float4 wb = *(const float4*)&ws[k][c0 + 4];
        float xr[4] = {xa.x, xa.y, xa.z, xa.w};
        float wr[8] = {wa.x, wa.y, wa.z, wa.w, wb.x, wb.y, wb.z, wb.w};
#pragma unroll
        for (int i = 0; i < 4; ++i)
#pragma unroll
            for (int j = 0; j < 8; ++j) acc[i][j] = fmaf(xr[i], wr[j], acc[i][j]);
    }
    float bias[8];
#pragma unroll
    for (int j = 0; j < 8; ++j) bias[j] = b[c0 + j];
#pragma unroll
    for (int i = 0; i < 4; ++i) {
        int gr = rb + r0 + i;
        if (gr < N) {
            float d = dis[gr];
            float4 o0, o1;
            o0.x = (acc[i][0] + bias[0]) * d; o0.y = (acc[i][1] + bias[1]) * d;
            o0.z = (acc[i][2] + bias[2]) * d; o0.w = (acc[i][3] + bias[3]) * d;
            o1.x = (acc[i][4] + bias[4]) * d; o1.y = (acc[i][5] + bias[5]) * d;
            o1.z = (acc[i][6] + bias[6]) * d; o1.w = (acc[i][7] + bias[7]) * d;
            *(float4*)&out[gr * 64 + c0]     = o0;
            *(float4*)&out[gr * 64 + c0 + 4] = o1;
        }
    }
}

// ---------------- CSR decode: for each row a, out[eid] = dis[a]*dis[b]*dot64(z[a], z[b]) ----------------
// wave per row; z[a] in registers (float4/lane, replicated across four 16-lane groups);
// 4 neighbors per iteration (one per group), 256 B coalesced z[b] load per group.

__global__ __launch_bounds__(256) void decode_csr_kernel(const int* __restrict__ rowptr,
                                                         const int* __restrict__ cols,
                                                         const int* __restrict__ eids,
                                                         const float* __restrict__ dis,
                                                         const float* __restrict__ z,
                                                         float* __restrict__ out, int N) {
    int r = blockIdx.x * 4 + (threadIdx.x >> 6);
    int lane = threadIdx.x & 63;
    if (r >= N) return;
    int s = rowptr[r], e = rowptr[r + 1];
    if (s == e) return;
    const int l16 = lane & 15;
    const int grp = lane >> 4;
    const float4* z4 = (const float4*)z;
    const float4 zr = z4[(size_t)r * 16 + l16];
    const float dr = dis[r];
#pragma unroll 2
    for (int j = s; j < e; j += 4) {
        int jj = j + grp;
        bool act = jj < e;
        int c = cols[act ? jj : (e - 1)];
        float4 vb = z4[(size_t)c * 16 + l16];
        float p = zr.x * vb.x + zr.y * vb.y + zr.z * vb.z + zr.w * vb.w;
        p += __shfl_xor(p, 8);
        p += __shfl_xor(p, 4);
        p += __shfl_xor(p, 2);
        p += __shfl_xor(p, 1);
        if (act && l16 == 0) {
            out[eids[jj]] = dr * dis[c] * p;
        }
    }
}

// ---------------- launch ----------------

extern "C" void kernel_launch(void* const* d_in, const int* in_sizes, int n_in,
                              void* d_out, int out_size, void* d_ws, size_t ws_size,
                              hipStream_t stream) {
    const float* x  = (const float*)d_in[0];
    const int*   pe = (const int*)d_in[1];
    const int*   ne = (const int*)d_in[2];
    const float* W1 = (const float*)d_in[3];
    const float* b1 = (const float*)d_in[4];
    const float* W2 = (const float*)d_in[5];
    const float* b2 = (const float*)d_in[6];
    float* outp = (float*)d_out;

    const int N  = in_sizes[0] / FIN;
    const int Ep = in_sizes[1] / 2;
    const int En = in_sizes[2] / 2;

    char* w = (char*)d_ws;
    size_t off = 0;
    auto alloc = [&](size_t bytes) {
        void* p = w + off;
        off = (off + bytes + 255) & ~(size_t)255;
        return p;
    };
    unsigned* deg   = (unsigned*)alloc((size_t)N * 4);
    unsigned* degN  = (unsigned*)alloc((size_t)N * 4);
    float* dis      = (float*)alloc((size_t)N * 4);
    int* rowptr     = (int*)alloc((size_t)(N + 1) * 4);
    int* cursor     = (int*)alloc((size_t)N * 4);
    int* rowptrN    = (int*)alloc((size_t)(N + 1) * 4);
    int* cursorN    = (int*)alloc((size_t)N * 4);
    int* blocksums  = (int*)alloc(((size_t)N / SCAN_BLK + 2) * 4);
    int* colsorted  = (int*)alloc((size_t)Ep * 4);
    int* eidP       = (int*)alloc((size_t)Ep * 4);
    int* colN       = (int*)alloc((size_t)En * 4);
    int* eidN       = (int*)alloc((size_t)En * 4);
    float* A        = (float*)alloc((size_t)N * 64 * 4);   // h, then h2 (col-side dis folded)
    float* B        = (float*)alloc((size_t)N * 64 * 4);   // agg1, then agg2

    const int nscan = (N + SCAN_BLK - 1) / SCAN_BLK;

    hipMemsetAsync(deg, 0, (size_t)N * 4, stream);
    hipMemsetAsync(degN, 0, (size_t)N * 4, stream);

    // pos CSR
    deg_kernel<<<(Ep + 255) / 256, 256, 0, stream>>>(pe, deg, Ep);
    dis_kernel<<<(N + 255) / 256, 256, 0, stream>>>(deg, dis, N);
    scan_block_kernel<<<nscan, 256, 0, stream>>>(deg, rowptr, blocksums, N);
    scan_sums_kernel<<<1, 64, 0, stream>>>(blocksums, nscan);
    scan_add_kernel<<<(N + 255) / 256, 256, 0, stream>>>(rowptr, cursor, blocksums, N, Ep);
    scatter_edges_kernel<<<(Ep + 255) / 256, 256, 0, stream>>>(pe, pe + Ep, cursor,
                                                               colsorted, eidP, 0, Ep);
    // neg CSR (for decode locality only)
    deg_kernel<<<(En + 255) / 256, 256, 0, stream>>>(ne, degN, En);
    scan_block_kernel<<<nscan, 256, 0, stream>>>(degN, rowptrN, blocksums, N);
    scan_sums_kernel<<<1, 64, 0, stream>>>(blocksums, nscan);
    scan_add_kernel<<<(N + 255) / 256, 256, 0, stream>>>(rowptrN, cursorN, blocksums, N, En);
    scatter_edges_kernel<<<(En + 255) / 256, 256, 0, stream>>>(ne, ne + En, cursorN,
                                                               colN, eidN, Ep, En);
    // layer 1
    gemm1_kernel<<<(N + 255) / 256, 256, 0, stream>>>(x, W1, b1, dis, A, N);
    gather_agg_kernel<<<(N + 3) / 4, 256, 0, stream>>>(rowptr, colsorted, A, B, N);
    // layer 2
    gemm2_kernel<<<(N + 127) / 128, 256, 0, stream>>>(B, dis, W2, b2, A, N);
    gather_agg_kernel<<<(N + 3) / 4, 256, 0, stream>>>(rowptr, colsorted, A, B, N);
    // decode (CSR order, scatter to original edge ids)
    decode_csr_kernel<<<(N + 3) / 4, 256, 0, stream>>>(rowptr, colsorted, eidP, dis, B, outp, N);
    decode_csr_kernel<<<(N + 3) / 4, 256, 0, stream>>>(rowptrN, colN, eidN, dis, B, outp, N);
}

// Round 5
// 725.945 us; speedup vs baseline: 1.2455x; 1.2455x over previous
//
#include <hip/hip_runtime.h>

#define FIN 256
#define FH  64
#define SCAN_BLK 1024

// ---------------- degree / normalization ----------------

__global__ __launch_bounds__(256) void deg_kernel(const int* __restrict__ rows,
                                                  unsigned* __restrict__ deg, int E) {
    int e = blockIdx.x * 256 + threadIdx.x;
    if (e < E) atomicAdd(&deg[rows[e]], 1u);
}

__global__ __launch_bounds__(256) void dis_kernel(const unsigned* __restrict__ deg,
                                                  float* __restrict__ dis, int N) {
    int i = blockIdx.x * 256 + threadIdx.x;
    if (i < N) {
        unsigned d = deg[i];
        dis[i] = d ? 1.0f / sqrtf((float)d) : 0.0f;
    }
}

// ---------------- exclusive scan of deg -> rowptr (3 kernels) ----------------

__global__ __launch_bounds__(256) void scan_block_kernel(const unsigned* __restrict__ deg,
                                                         int* __restrict__ rowptr,
                                                         int* __restrict__ blocksums, int N) {
    __shared__ int wsum[4];
    const int t = threadIdx.x;
    const int base = blockIdx.x * SCAN_BLK + t * 4;
    int d0 = 0, d1 = 0, d2 = 0, d3 = 0;
    if (base + 0 < N) d0 = (int)deg[base + 0];
    if (base + 1 < N) d1 = (int)deg[base + 1];
    if (base + 2 < N) d2 = (int)deg[base + 2];
    if (base + 3 < N) d3 = (int)deg[base + 3];
    const int tot = d0 + d1 + d2 + d3;
    const int lane = t & 63, wv = t >> 6;
    int inc = tot;
#pragma unroll
    for (int off = 1; off < 64; off <<= 1) {
        int v = __shfl_up(inc, off, 64);
        if (lane >= off) inc += v;
    }
    if (lane == 63) wsum[wv] = inc;
    __syncthreads();
    int woff = 0;
    for (int w = 0; w < wv; ++w) woff += wsum[w];
    const int ex = woff + inc - tot;   // exclusive prefix of this thread within block
    if (base + 0 < N) rowptr[base + 0] = ex;
    if (base + 1 < N) rowptr[base + 1] = ex + d0;
    if (base + 2 < N) rowptr[base + 2] = ex + d0 + d1;
    if (base + 3 < N) rowptr[base + 3] = ex + d0 + d1 + d2;
    if (t == 255) blocksums[blockIdx.x] = woff + inc;   // block total
}

__global__ void scan_sums_kernel(int* __restrict__ blocksums, int nb) {
    if (threadIdx.x == 0 && blockIdx.x == 0) {
        int run = 0;
        for (int i = 0; i < nb; ++i) { int v = blocksums[i]; blocksums[i] = run; run += v; }
    }
}

__global__ __launch_bounds__(256) void scan_add_kernel(int* __restrict__ rowptr,
                                                       int* __restrict__ cursor,
                                                       const int* __restrict__ blocksums,
                                                       int N, int E) {
    int i = blockIdx.x * 256 + threadIdx.x;
    if (i < N) {
        int v = rowptr[i] + blocksums[i / SCAN_BLK];
        rowptr[i] = v;
        cursor[i] = v;
    }
    if (i == 0) rowptr[N] = E;
}

// ---------------- counting-sort edges into CSR col array ----------------

__global__ __launch_bounds__(256) void scatter_edges_kernel(const int* __restrict__ rows,
                                                            const int* __restrict__ cols,
                                                            int* __restrict__ cursor,
                                                            int* __restrict__ colOut, int E) {
    int e = blockIdx.x * 256 + threadIdx.x;
    if (e < E) {
        int p = atomicAdd(&cursor[rows[e]], 1);
        colOut[p] = cols[e];
    }
}

// ---------------- GEMM1: out[N][64] = (x[N][256] @ W[256][64] + b) * dis[r] ----------------

__global__ __launch_bounds__(256) void gemm1_kernel(const float* __restrict__ x,
                                                    const float* __restrict__ W,
                                                    const float* __restrict__ b,
                                                    const float* __restrict__ dis,
                                                    float* __restrict__ out, int N) {
    __shared__ float xs[32][260];
    __shared__ float ws[32][64];
    const int t = threadIdx.x;
    const int rb = blockIdx.x * 256;
    const int rg = t >> 3, cg = t & 7;
    const int r0 = rg * 8, c0 = cg * 8;
    float acc[8][8];
#pragma unroll
    for (int i = 0; i < 8; ++i)
#pragma unroll
        for (int j = 0; j < 8; ++j) acc[i][j] = 0.f;

    const float4* x4 = (const float4*)x;
    const int kk = (t & 7) * 4;
    const int rloc = t >> 3;

    for (int k0 = 0; k0 < FIN; k0 += 32) {
        __syncthreads();
        {
            const float4* w4 = (const float4*)(W + k0 * 64);
            float4* wl = (float4*)&ws[0][0];
            wl[t]       = w4[t];
            wl[t + 256] = w4[t + 256];
        }
#pragma unroll
        for (int p = 0; p < 8; ++p) {
            int r = rloc + p * 32;
            int gr = rb + r; if (gr >= N) gr = N - 1;
            float4 v = x4[gr * 64 + (k0 >> 2) + (t & 7)];
            xs[kk + 0][r] = v.x; xs[kk + 1][r] = v.y;
            xs[kk + 2][r] = v.z; xs[kk + 3][r] = v.w;
        }
        __syncthreads();
#pragma unroll
        for (int k = 0; k < 32; ++k) {
            float4 xa = *(const float4*)&xs[k][r0];
            float4 xb = *(const float4*)&xs[k][r0 + 4];
            float4 wa = *(const float4*)&ws[k][c0];
            float4 wb = *(const float4*)&ws[k][c0 + 4];
            float xr[8] = {xa.x, xa.y, xa.z, xa.w, xb.x, xb.y, xb.z, xb.w};
            float wr[8] = {wa.x, wa.y, wa.z, wa.w, wb.x, wb.y, wb.z, wb.w};
#pragma unroll
            for (int i = 0; i < 8; ++i)
#pragma unroll
                for (int j = 0; j < 8; ++j) acc[i][j] = fmaf(xr[i], wr[j], acc[i][j]);
        }
    }
    float bias[8];
#pragma unroll
    for (int j = 0; j < 8; ++j) bias[j] = b[c0 + j];
#pragma unroll
    for (int i = 0; i < 8; ++i) {
        int gr = rb + r0 + i;
        if (gr < N) {
            float d = dis[gr];
            float4 o0, o1;
            o0.x = (acc[i][0] + bias[0]) * d; o0.y = (acc[i][1] + bias[1]) * d;
            o0.z = (acc[i][2] + bias[2]) * d; o0.w = (acc[i][3] + bias[3]) * d;
            o1.x = (acc[i][4] + bias[4]) * d; o1.y = (acc[i][5] + bias[5]) * d;
            o1.z = (acc[i][6] + bias[6]) * d; o1.w = (acc[i][7] + bias[7]) * d;
            *(float4*)&out[gr * 64 + c0]     = o0;
            *(float4*)&out[gr * 64 + c0 + 4] = o1;
        }
    }
}

// ---------------- CSR gather aggregation: out[r] = sum over neighbors of h[c] ----------------
// one 64-lane wave per row, lane = feature; 4 independent loads in flight (ILP).

__global__ __launch_bounds__(256) void gather_agg_kernel(const int* __restrict__ rowptr,
                                                         const int* __restrict__ cols,
                                                         const float* __restrict__ h,
                                                         float* __restrict__ out, int N) {
    int r = blockIdx.x * 4 + (threadIdx.x >> 6);
    int lane = threadIdx.x & 63;
    if (r >= N) return;
    int s = rowptr[r], e = rowptr[r + 1];
    float acc0 = 0.f, acc1 = 0.f, acc2 = 0.f, acc3 = 0.f;
    for (int base = s; base < e; base += 64) {
        int n = e - base; if (n > 64) n = 64;
        int idx = (lane < n) ? cols[base + lane] : 0;
        int j = 0;
        for (; j + 3 < n; j += 4) {
            int c0 = __shfl(idx, j, 64);
            int c1 = __shfl(idx, j + 1, 64);
            int c2 = __shfl(idx, j + 2, 64);
            int c3 = __shfl(idx, j + 3, 64);
            acc0 += h[(size_t)c0 * 64 + lane];
            acc1 += h[(size_t)c1 * 64 + lane];
            acc2 += h[(size_t)c2 * 64 + lane];
            acc3 += h[(size_t)c3 * 64 + lane];
        }
        for (; j < n; ++j) {
            int c0 = __shfl(idx, j, 64);
            acc0 += h[(size_t)c0 * 64 + lane];
        }
    }
    out[(size_t)r * 64 + lane] = (acc0 + acc1) + (acc2 + acc3);
}

// ---------------- GEMM2: out[N][64] = (relu(dis[r]*agg[r]) @ W[64][64] + b) * dis[r] ----------------

__global__ __launch_bounds__(256) void gemm2_kernel(const float* __restrict__ agg,
                                                    const float* __restrict__ dis,
                                                    const float* __restrict__ W,
                                                    const float* __restrict__ b,
                                                    float* __restrict__ out, int N) {
    __shared__ float xs[64][132];
    __shared__ float ws[64][64];
    const int t = threadIdx.x;
    const int rb = blockIdx.x * 128;
    {
        const float4* w4 = (const float4*)W;
        float4* wl = (float4*)&ws[0][0];
#pragma unroll
        for (int p = 0; p < 4; ++p) wl[p * 256 + t] = w4[p * 256 + t];
    }
    {
        const float4* a4 = (const float4*)agg;
        const int c4 = (t & 15) * 4;
        const int rloc = t >> 4;
#pragma unroll
        for (int p = 0; p < 8; ++p) {
            int r = rloc + p * 16;
            int gr = rb + r; if (gr >= N) gr = N - 1;
            float d = dis[gr];
            float4 v = a4[gr * 16 + (t & 15)];
            xs[c4 + 0][r] = fmaxf(v.x * d, 0.f);
            xs[c4 + 1][r] = fmaxf(v.y * d, 0.f);
            xs[c4 + 2][r] = fmaxf(v.z * d, 0.f);
            xs[c4 + 3][r] = fmaxf(v.w * d, 0.f);
        }
    }
    __syncthreads();
    const int rg = t >> 3, cg = t & 7;
    const int r0 = rg * 4, c0 = cg * 8;
    float acc[4][8];
#pragma unroll
    for (int i = 0; i < 4; ++i)
#pragma unroll
        for (int j = 0; j < 8; ++j) acc[i][j] = 0.f;
#pragma unroll 16
    for (int k = 0; k < 64; ++k) {
        float4 xa = *(const float4*)&xs[k][r0];
        float4 wa = *(const float4*)&ws[k][c0];
        float4 wb = *(const float4*)&ws[k][c0 + 4];
        float xr[4] = {xa.x, xa.y, xa.z, xa.w};
        float wr[8] = {wa.x, wa.y, wa.z, wa.w, wb.x, wb.y, wb.z, wb.w};
#pragma unroll
        for (int i = 0; i < 4; ++i)
#pragma unroll
            for (int j = 0; j < 8; ++j) acc[i][j] = fmaf(xr[i], wr[j], acc[i][j]);
    }
    float bias[8];
#pragma unroll
    for (int j = 0; j < 8; ++j) bias[j] = b[c0 + j];
#pragma unroll
    for (int i = 0; i < 4; ++i) {
        int gr = rb + r0 + i;
        if (gr < N) {
            float d = dis[gr];
            float4 o0, o1;
            o0.x = (acc[i][0] + bias[0]) * d; o0.y = (acc[i][1] + bias[1]) * d;
            o0.z = (acc[i][2] + bias[2]) * d; o0.w = (acc[i][3] + bias[3]) * d;
            o1.x = (acc[i][4] + bias[4]) * d; o1.y = (acc[i][5] + bias[5]) * d;
            o1.z = (acc[i][6] + bias[6]) * d; o1.w = (acc[i][7] + bias[7]) * d;
            *(float4*)&out[gr * 64 + c0]     = o0;
            *(float4*)&out[gr * 64 + c0 + 4] = o1;
        }
    }
}

// ---------------- decode: out[e] = dis[a]*dis[b] * dot64(z[a], z[b]) ----------------
// 16 lanes per edge, 4 edges per group in flight (8 independent 256B loads).

__global__ __launch_bounds__(256) void decode_kernel(const int* __restrict__ pe,
                                                     const int* __restrict__ ne,
                                                     const float* __restrict__ dis,
                                                     const float* __restrict__ z,
                                                     float* __restrict__ out, int Ep, int En) {
    const int t = threadIdx.x;
    const int grp = t >> 4;      // 0..15
    const int l16 = t & 15;
    const int Etot = Ep + En;
    const int base = blockIdx.x * 64 + grp;
    const float4* z4 = (const float4*)z;

    int a[4], b[4];
    bool v[4];
#pragma unroll
    for (int q = 0; q < 4; ++q) {
        int e = base + q * 16;
        v[q] = e < Etot;
        a[q] = 0; b[q] = 0;
        if (v[q]) {
            if (e < Ep) { a[q] = pe[e]; b[q] = pe[Ep + e]; }
            else        { int j = e - Ep; a[q] = ne[j]; b[q] = ne[En + j]; }
        }
    }
    float4 va[4], vb[4];
#pragma unroll
    for (int q = 0; q < 4; ++q) {
        va[q] = z4[(size_t)a[q] * 16 + l16];
        vb[q] = z4[(size_t)b[q] * 16 + l16];
    }
    float s[4];
#pragma unroll
    for (int q = 0; q < 4; ++q) {
        float p = va[q].x * vb[q].x + va[q].y * vb[q].y
                + va[q].z * vb[q].z + va[q].w * vb[q].w;
        p += __shfl_xor(p, 8);
        p += __shfl_xor(p, 4);
        p += __shfl_xor(p, 2);
        p += __shfl_xor(p, 1);
        s[q] = p;
    }
#pragma unroll
    for (int q = 0; q < 4; ++q) {
        if (v[q] && l16 == 0) {
            out[base + q * 16] = dis[a[q]] * dis[b[q]] * s[q];
        }
    }
}

// ---------------- launch ----------------

extern "C" void kernel_launch(void* const* d_in, const int* in_sizes, int n_in,
                              void* d_out, int out_size, void* d_ws, size_t ws_size,
                              hipStream_t stream) {
    const float* x  = (const float*)d_in[0];
    const int*   pe = (const int*)d_in[1];
    const int*   ne = (const int*)d_in[2];
    const float* W1 = (const float*)d_in[3];
    const float* b1 = (const float*)d_in[4];
    const float* W2 = (const float*)d_in[5];
    const float* b2 = (const float*)d_in[6];
    float* outp = (float*)d_out;

    const int N  = in_sizes[0] / FIN;
    const int Ep = in_sizes[1] / 2;
    const int En = in_sizes[2] / 2;

    char* w = (char*)d_ws;
    size_t off = 0;
    auto alloc = [&](size_t bytes) {
        void* p = w + off;
        off = (off + bytes + 255) & ~(size_t)255;
        return p;
    };
    unsigned* deg   = (unsigned*)alloc((size_t)N * 4);
    float* dis      = (float*)alloc((size_t)N * 4);
    int* rowptr     = (int*)alloc((size_t)(N + 1) * 4);
    int* cursor     = (int*)alloc((size_t)N * 4);
    int* blocksums  = (int*)alloc(((size_t)N / SCAN_BLK + 2) * 4);
    int* colsorted  = (int*)alloc((size_t)Ep * 4);
    float* A        = (float*)alloc((size_t)N * 64 * 4);   // h, then h2 (col-side dis folded)
    float* B        = (float*)alloc((size_t)N * 64 * 4);   // agg1, then agg2

    const int nscan = (N + SCAN_BLK - 1) / SCAN_BLK;

    hipMemsetAsync(deg, 0, (size_t)N * 4, stream);

    // pos CSR
    deg_kernel<<<(Ep + 255) / 256, 256, 0, stream>>>(pe, deg, Ep);
    dis_kernel<<<(N + 255) / 256, 256, 0, stream>>>(deg, dis, N);
    scan_block_kernel<<<nscan, 256, 0, stream>>>(deg, rowptr, blocksums, N);
    scan_sums_kernel<<<1, 64, 0, stream>>>(blocksums, nscan);
    scan_add_kernel<<<(N + 255) / 256, 256, 0, stream>>>(rowptr, cursor, blocksums, N, Ep);
    scatter_edges_kernel<<<(Ep + 255) / 256, 256, 0, stream>>>(pe, pe + Ep, cursor, colsorted, Ep);
    // layer 1
    gemm1_kernel<<<(N + 255) / 256, 256, 0, stream>>>(x, W1, b1, dis, A, N);
    gather_agg_kernel<<<(N + 3) / 4, 256, 0, stream>>>(rowptr, colsorted, A, B, N);
    // layer 2
    gemm2_kernel<<<(N + 127) / 128, 256, 0, stream>>>(B, dis, W2, b2, A, N);
    gather_agg_kernel<<<(N + 3) / 4, 256, 0, stream>>>(rowptr, colsorted, A, B, N);
    // decode
    decode_kernel<<<(Ep + En + 63) / 64, 256, 0, stream>>>(pe, ne, dis, B, outp, Ep, En);
}

// Round 6
// 665.153 us; speedup vs baseline: 1.3593x; 1.0914x over previous
//
#include <hip/hip_runtime.h>

#define FIN 256
#define FH  64
#define SCAN_BLK 1024
#define NCHUNK 8

// ---------------- degree ----------------

__global__ __launch_bounds__(256) void deg_kernel(const int* __restrict__ rows,
                                                  unsigned* __restrict__ deg, int E) {
    int e = blockIdx.x * 256 + threadIdx.x;
    if (e < E) atomicAdd(&deg[rows[e]], 1u);
}

// ---------------- scan: per-block scan of deg -> rowptr (block-local) + block totals ----------------

__global__ __launch_bounds__(256) void scan_block_kernel(const unsigned* __restrict__ deg,
                                                         int* __restrict__ rowptr,
                                                         int* __restrict__ blocksums, int N) {
    __shared__ int wsum[4];
    const int t = threadIdx.x;
    const int base = blockIdx.x * SCAN_BLK + t * 4;
    int d0 = 0, d1 = 0, d2 = 0, d3 = 0;
    if (base + 0 < N) d0 = (int)deg[base + 0];
    if (base + 1 < N) d1 = (int)deg[base + 1];
    if (base + 2 < N) d2 = (int)deg[base + 2];
    if (base + 3 < N) d3 = (int)deg[base + 3];
    const int tot = d0 + d1 + d2 + d3;
    const int lane = t & 63, wv = t >> 6;
    int inc = tot;
#pragma unroll
    for (int off = 1; off < 64; off <<= 1) {
        int v = __shfl_up(inc, off, 64);
        if (lane >= off) inc += v;
    }
    if (lane == 63) wsum[wv] = inc;
    __syncthreads();
    int woff = 0;
    for (int w = 0; w < wv; ++w) woff += wsum[w];
    const int ex = woff + inc - tot;   // exclusive prefix of this thread within block
    if (base + 0 < N) rowptr[base + 0] = ex;
    if (base + 1 < N) rowptr[base + 1] = ex + d0;
    if (base + 2 < N) rowptr[base + 2] = ex + d0 + d1;
    if (base + 3 < N) rowptr[base + 3] = ex + d0 + d1 + d2;
    if (t == 255) blocksums[blockIdx.x] = woff + inc;   // block TOTAL (unscanned)
}

// ---------------- scan_add: add cross-block prefix; also emit cursor and dis ----------------
// Each 256-thread block lies within one SCAN_BLK chunk, so one prefix per block.

__global__ __launch_bounds__(256) void scan_add_kernel(int* __restrict__ rowptr,
                                                       int* __restrict__ cursor,
                                                       const unsigned* __restrict__ deg,
                                                       float* __restrict__ dis,
                                                       const int* __restrict__ blocksums,
                                                       int nb, int N, int E) {
    __shared__ int pre;
    const int t = threadIdx.x;
    const int i0 = blockIdx.x * 256;
    const int c0 = i0 / SCAN_BLK;
    if (t == 0) {
        int s = 0;
        for (int k = 0; k < c0; ++k) s += blocksums[k];
        pre = s;
    }
    __syncthreads();
    int i = i0 + t;
    if (i < N) {
        int v = rowptr[i] + pre;
        rowptr[i] = v;
        cursor[i] = v;
        unsigned d = deg[i];
        dis[i] = d ? 1.0f / sqrtf((float)d) : 0.0f;
    }
    if (i == 0) rowptr[N] = E;
}

// ---------------- counting-sort edges into CSR col array, row-range chunked ----------------
// chunk = blockIdx & 7 -> round-robins to one XCD (dispatch heuristic); each chunk's
// ~800 KB destination region stays L2-resident on one XCD so dirty lines fill fully.
// Any chunk assignment is correctness-neutral (atomic cursor); chunking is locality only.

__global__ __launch_bounds__(256) void scatter_edges_kernel(const int* __restrict__ rows,
                                                            const int* __restrict__ cols,
                                                            int* __restrict__ cursor,
                                                            int* __restrict__ colOut,
                                                            float chunk_scale, int E) {
    const int chunk = blockIdx.x & (NCHUNK - 1);
    const int eb = blockIdx.x >> 3;
    int e = eb * 256 + threadIdx.x;
    if (e >= E) return;
    int r = rows[e];
    int rc = (int)((float)r * chunk_scale);
    rc = rc > (NCHUNK - 1) ? (NCHUNK - 1) : rc;
    if (rc == chunk) {
        int p = atomicAdd(&cursor[r], 1);
        colOut[p] = cols[e];
    }
}

// ---------------- GEMM1: out[N][64] = (x[N][256] @ W[256][64] + b) * dis[r] ----------------

__global__ __launch_bounds__(256) void gemm1_kernel(const float* __restrict__ x,
                                                    const float* __restrict__ W,
                                                    const float* __restrict__ b,
                                                    const float* __restrict__ dis,
                                                    float* __restrict__ out, int N) {
    __shared__ float xs[32][260];
    __shared__ float ws[32][64];
    const int t = threadIdx.x;
    const int rb = blockIdx.x * 256;
    const int rg = t >> 3, cg = t & 7;
    const int r0 = rg * 8, c0 = cg * 8;
    float acc[8][8];
#pragma unroll
    for (int i = 0; i < 8; ++i)
#pragma unroll
        for (int j = 0; j < 8; ++j) acc[i][j] = 0.f;

    const float4* x4 = (const float4*)x;
    const int kk = (t & 7) * 4;
    const int rloc = t >> 3;

    for (int k0 = 0; k0 < FIN; k0 += 32) {
        __syncthreads();
        {
            const float4* w4 = (const float4*)(W + k0 * 64);
            float4* wl = (float4*)&ws[0][0];
            wl[t]       = w4[t];
            wl[t + 256] = w4[t + 256];
        }
#pragma unroll
        for (int p = 0; p < 8; ++p) {
            int r = rloc + p * 32;
            int gr = rb + r; if (gr >= N) gr = N - 1;
            float4 v = x4[gr * 64 + (k0 >> 2) + (t & 7)];
            xs[kk + 0][r] = v.x; xs[kk + 1][r] = v.y;
            xs[kk + 2][r] = v.z; xs[kk + 3][r] = v.w;
        }
        __syncthreads();
#pragma unroll
        for (int k = 0; k < 32; ++k) {
            float4 xa = *(const float4*)&xs[k][r0];
            float4 xb = *(const float4*)&xs[k][r0 + 4];
            float4 wa = *(const float4*)&ws[k][c0];
            float4 wb = *(const float4*)&ws[k][c0 + 4];
            float xr[8] = {xa.x, xa.y, xa.z, xa.w, xb.x, xb.y, xb.z, xb.w};
            float wr[8] = {wa.x, wa.y, wa.z, wa.w, wb.x, wb.y, wb.z, wb.w};
#pragma unroll
            for (int i = 0; i < 8; ++i)
#pragma unroll
                for (int j = 0; j < 8; ++j) acc[i][j] = fmaf(xr[i], wr[j], acc[i][j]);
        }
    }
    float bias[8];
#pragma unroll
    for (int j = 0; j < 8; ++j) bias[j] = b[c0 + j];
#pragma unroll
    for (int i = 0; i < 8; ++i) {
        int gr = rb + r0 + i;
        if (gr < N) {
            float d = dis[gr];
            float4 o0, o1;
            o0.x = (acc[i][0] + bias[0]) * d; o0.y = (acc[i][1] + bias[1]) * d;
            o0.z = (acc[i][2] + bias[2]) * d; o0.w = (acc[i][3] + bias[3]) * d;
            o1.x = (acc[i][4] + bias[4]) * d; o1.y = (acc[i][5] + bias[5]) * d;
            o1.z = (acc[i][6] + bias[6]) * d; o1.w = (acc[i][7] + bias[7]) * d;
            *(float4*)&out[gr * 64 + c0]     = o0;
            *(float4*)&out[gr * 64 + c0 + 4] = o1;
        }
    }
}

// ---------------- CSR gather aggregation: out[r] = sum over neighbors of h[c] ----------------
// one 64-lane wave per row, lane = feature; 8 independent loads in flight (ILP).

__global__ __launch_bounds__(256) void gather_agg_kernel(const int* __restrict__ rowptr,
                                                         const int* __restrict__ cols,
                                                         const float* __restrict__ h,
                                                         float* __restrict__ out, int N) {
    int r = blockIdx.x * 4 + (threadIdx.x >> 6);
    int lane = threadIdx.x & 63;
    if (r >= N) return;
    int s = rowptr[r], e = rowptr[r + 1];
    float acc0 = 0.f, acc1 = 0.f, acc2 = 0.f, acc3 = 0.f;
    float acc4 = 0.f, acc5 = 0.f, acc6 = 0.f, acc7 = 0.f;
    for (int base = s; base < e; base += 64) {
        int n = e - base; if (n > 64) n = 64;
        int idx = (lane < n) ? cols[base + lane] : 0;
        int j = 0;
        for (; j + 7 < n; j += 8) {
            int c0 = __shfl(idx, j, 64);
            int c1 = __shfl(idx, j + 1, 64);
            int c2 = __shfl(idx, j + 2, 64);
            int c3 = __shfl(idx, j + 3, 64);
            int c4 = __shfl(idx, j + 4, 64);
            int c5 = __shfl(idx, j + 5, 64);
            int c6 = __shfl(idx, j + 6, 64);
            int c7 = __shfl(idx, j + 7, 64);
            acc0 += h[(size_t)c0 * 64 + lane];
            acc1 += h[(size_t)c1 * 64 + lane];
            acc2 += h[(size_t)c2 * 64 + lane];
            acc3 += h[(size_t)c3 * 64 + lane];
            acc4 += h[(size_t)c4 * 64 + lane];
            acc5 += h[(size_t)c5 * 64 + lane];
            acc6 += h[(size_t)c6 * 64 + lane];
            acc7 += h[(size_t)c7 * 64 + lane];
        }
        for (; j + 3 < n; j += 4) {
            int c0 = __shfl(idx, j, 64);
            int c1 = __shfl(idx, j + 1, 64);
            int c2 = __shfl(idx, j + 2, 64);
            int c3 = __shfl(idx, j + 3, 64);
            acc0 += h[(size_t)c0 * 64 + lane];
            acc1 += h[(size_t)c1 * 64 + lane];
            acc2 += h[(size_t)c2 * 64 + lane];
            acc3 += h[(size_t)c3 * 64 + lane];
        }
        for (; j < n; ++j) {
            int c0 = __shfl(idx, j, 64);
            acc0 += h[(size_t)c0 * 64 + lane];
        }
    }
    out[(size_t)r * 64 + lane] = ((acc0 + acc1) + (acc2 + acc3)) + ((acc4 + acc5) + (acc6 + acc7));
}

// ---------------- GEMM2: out[N][64] = (relu(dis[r]*agg[r]) @ W[64][64] + b) * dis[r] ----------------

__global__ __launch_bounds__(256) void gemm2_kernel(const float* __restrict__ agg,
                                                    const float* __restrict__ dis,
                                                    const float* __restrict__ W,
                                                    const float* __restrict__ b,
                                                    float* __restrict__ out, int N) {
    __shared__ float xs[64][132];
    __shared__ float ws[64][64];
    const int t = threadIdx.x;
    const int rb = blockIdx.x * 128;
    {
        const float4* w4 = (const float4*)W;
        float4* wl = (float4*)&ws[0][0];
#pragma unroll
        for (int p = 0; p < 4; ++p) wl[p * 256 + t] = w4[p * 256 + t];
    }
    {
        const float4* a4 = (const float4*)agg;
        const int c4 = (t & 15) * 4;
        const int rloc = t >> 4;
#pragma unroll
        for (int p = 0; p < 8; ++p) {
            int r = rloc + p * 16;
            int gr = rb + r; if (gr >= N) gr = N - 1;
            float d = dis[gr];
            float4 v = a4[gr * 16 + (t & 15)];
            xs[c4 + 0][r] = fmaxf(v.x * d, 0.f);
            xs[c4 + 1][r] = fmaxf(v.y * d, 0.f);
            xs[c4 + 2][r] = fmaxf(v.z * d, 0.f);
            xs[c4 + 3][r] = fmaxf(v.w * d, 0.f);
        }
    }
    __syncthreads();
    const int rg = t >> 3, cg = t & 7;
    const int r0 = rg * 4, c0 = cg * 8;
    float acc[4][8];
#pragma unroll
    for (int i = 0; i < 4; ++i)
#pragma unroll
        for (int j = 0; j < 8; ++j) acc[i][j] = 0.f;
#pragma unroll 16
    for (int k = 0; k < 64; ++k) {
        float4 xa = *(const float4*)&xs[k][r0];
        float4 wa = *(const float4*)&ws[k][c0];
        float4 wb = *(const float4*)&ws[k][c0 + 4];
        float xr[4] = {xa.x, xa.y, xa.z, xa.w};
        float wr[8] = {wa.x, wa.y, wa.z, wa.w, wb.x, wb.y, wb.z, wb.w};
#pragma unroll
        for (int i = 0; i < 4; ++i)
#pragma unroll
            for (int j = 0; j < 8; ++j) acc[i][j] = fmaf(xr[i], wr[j], acc[i][j]);
    }
    float bias[8];
#pragma unroll
    for (int j = 0; j < 8; ++j) bias[j] = b[c0 + j];
#pragma unroll
    for (int i = 0; i < 4; ++i) {
        int gr = rb + r0 + i;
        if (gr < N) {
            float d = dis[gr];
            float4 o0, o1;
            o0.x = (acc[i][0] + bias[0]) * d; o0.y = (acc[i][1] + bias[1]) * d;
            o0.z = (acc[i][2] + bias[2]) * d; o0.w = (acc[i][3] + bias[3]) * d;
            o1.x = (acc[i][4] + bias[4]) * d; o1.y = (acc[i][5] + bias[5]) * d;
            o1.z = (acc[i][6] + bias[6]) * d; o1.w = (acc[i][7] + bias[7]) * d;
            *(float4*)&out[gr * 64 + c0]     = o0;
            *(float4*)&out[gr * 64 + c0 + 4] = o1;
        }
    }
}

// ---------------- decode: out[e] = dis[a]*dis[b] * dot64(z[a], z[b]) ----------------
// 16 lanes per edge, 4 edges per group in flight (8 independent 256B loads).

__global__ __launch_bounds__(256) void decode_kernel(const int* __restrict__ pe,
                                                     const int* __restrict__ ne,
                                                     const float* __restrict__ dis,
                                                     const float* __restrict__ z,
                                                     float* __restrict__ out, int Ep, int En) {
    const int t = threadIdx.x;
    const int grp = t >> 4;      // 0..15
    const int l16 = t & 15;
    const int Etot = Ep + En;
    const int base = blockIdx.x * 64 + grp;
    const float4* z4 = (const float4*)z;

    int a[4], b[4];
    bool v[4];
#pragma unroll
    for (int q = 0; q < 4; ++q) {
        int e = base + q * 16;
        v[q] = e < Etot;
        a[q] = 0; b[q] = 0;
        if (v[q]) {
            if (e < Ep) { a[q] = pe[e]; b[q] = pe[Ep + e]; }
            else        { int j = e - Ep; a[q] = ne[j]; b[q] = ne[En + j]; }
        }
    }
    float4 va[4], vb[4];
#pragma unroll
    for (int q = 0; q < 4; ++q) {
        va[q] = z4[(size_t)a[q] * 16 + l16];
        vb[q] = z4[(size_t)b[q] * 16 + l16];
    }
    float s[4];
#pragma unroll
    for (int q = 0; q < 4; ++q) {
        float p = va[q].x * vb[q].x + va[q].y * vb[q].y
                + va[q].z * vb[q].z + va[q].w * vb[q].w;
        p += __shfl_xor(p, 8);
        p += __shfl_xor(p, 4);
        p += __shfl_xor(p, 2);
        p += __shfl_xor(p, 1);
        s[q] = p;
    }
#pragma unroll
    for (int q = 0; q < 4; ++q) {
        if (v[q] && l16 == 0) {
            out[base + q * 16] = dis[a[q]] * dis[b[q]] * s[q];
        }
    }
}

// ---------------- launch ----------------

extern "C" void kernel_launch(void* const* d_in, const int* in_sizes, int n_in,
                              void* d_out, int out_size, void* d_ws, size_t ws_size,
                              hipStream_t stream) {
    const float* x  = (const float*)d_in[0];
    const int*   pe = (const int*)d_in[1];
    const int*   ne = (const int*)d_in[2];
    const float* W1 = (const float*)d_in[3];
    const float* b1 = (const float*)d_in[4];
    const float* W2 = (const float*)d_in[5];
    const float* b2 = (const float*)d_in[6];
    float* outp = (float*)d_out;

    const int N  = in_sizes[0] / FIN;
    const int Ep = in_sizes[1] / 2;
    const int En = in_sizes[2] / 2;

    char* w = (char*)d_ws;
    size_t off = 0;
    auto alloc = [&](size_t bytes) {
        void* p = w + off;
        off = (off + bytes + 255) & ~(size_t)255;
        return p;
    };
    unsigned* deg   = (unsigned*)alloc((size_t)N * 4);
    float* dis      = (float*)alloc((size_t)N * 4);
    int* rowptr     = (int*)alloc((size_t)(N + 1) * 4);
    int* cursor     = (int*)alloc((size_t)N * 4);
    int* blocksums  = (int*)alloc(((size_t)N / SCAN_BLK + 2) * 4);
    int* colsorted  = (int*)alloc((size_t)Ep * 4);
    float* A        = (float*)alloc((size_t)N * 64 * 4);   // h, then h2 (col-side dis folded)
    float* B        = (float*)alloc((size_t)N * 64 * 4);   // agg1, then agg2

    const int nscan = (N + SCAN_BLK - 1) / SCAN_BLK;
    const int nEdgeBlocks = (Ep + 255) / 256;

    hipMemsetAsync(deg, 0, (size_t)N * 4, stream);

    // CSR build (pos edges)
    deg_kernel<<<nEdgeBlocks, 256, 0, stream>>>(pe, deg, Ep);
    scan_block_kernel<<<nscan, 256, 0, stream>>>(deg, rowptr, blocksums, N);
    scan_add_kernel<<<(N + 255) / 256, 256, 0, stream>>>(rowptr, cursor, deg, dis,
                                                         blocksums, nscan, N, Ep);
    scatter_edges_kernel<<<nEdgeBlocks * NCHUNK, 256, 0, stream>>>(
        pe, pe + Ep, cursor, colsorted, (float)NCHUNK / (float)N, Ep);
    // layer 1
    gemm1_kernel<<<(N + 255) / 256, 256, 0, stream>>>(x, W1, b1, dis, A, N);
    gather_agg_kernel<<<(N + 3) / 4, 256, 0, stream>>>(rowptr, colsorted, A, B, N);
    // layer 2
    gemm2_kernel<<<(N + 127) / 128, 256, 0, stream>>>(B, dis, W2, b2, A, N);
    gather_agg_kernel<<<(N + 3) / 4, 256, 0, stream>>>(rowptr, colsorted, A, B, N);
    // decode
    decode_kernel<<<(Ep + En + 63) / 64, 256, 0, stream>>>(pe, ne, dis, B, outp, Ep, En);
}

// Round 7
// 655.252 us; speedup vs baseline: 1.3798x; 1.0151x over previous
//
#include <hip/hip_runtime.h>

#define FIN 256
#define FH  64
#define SCAN_BLK 1024
#define NCHUNK 8

// ---------------- degree ----------------

__global__ __launch_bounds__(256) void deg_kernel(const int* __restrict__ rows,
                                                  unsigned* __restrict__ deg, int E) {
    int e = blockIdx.x * 256 + threadIdx.x;
    if (e < E) atomicAdd(&deg[rows[e]], 1u);
}

// ---------------- scan: per-block scan of deg -> rowptr (block-local) + block totals ----------------

__global__ __launch_bounds__(256) void scan_block_kernel(const unsigned* __restrict__ deg,
                                                         int* __restrict__ rowptr,
                                                         int* __restrict__ blocksums, int N) {
    __shared__ int wsum[4];
    const int t = threadIdx.x;
    const int base = blockIdx.x * SCAN_BLK + t * 4;
    int d0 = 0, d1 = 0, d2 = 0, d3 = 0;
    if (base + 0 < N) d0 = (int)deg[base + 0];
    if (base + 1 < N) d1 = (int)deg[base + 1];
    if (base + 2 < N) d2 = (int)deg[base + 2];
    if (base + 3 < N) d3 = (int)deg[base + 3];
    const int tot = d0 + d1 + d2 + d3;
    const int lane = t & 63, wv = t >> 6;
    int inc = tot;
#pragma unroll
    for (int off = 1; off < 64; off <<= 1) {
        int v = __shfl_up(inc, off, 64);
        if (lane >= off) inc += v;
    }
    if (lane == 63) wsum[wv] = inc;
    __syncthreads();
    int woff = 0;
    for (int w = 0; w < wv; ++w) woff += wsum[w];
    const int ex = woff + inc - tot;   // exclusive prefix of this thread within block
    if (base + 0 < N) rowptr[base + 0] = ex;
    if (base + 1 < N) rowptr[base + 1] = ex + d0;
    if (base + 2 < N) rowptr[base + 2] = ex + d0 + d1;
    if (base + 3 < N) rowptr[base + 3] = ex + d0 + d1 + d2;
    if (t == 255) blocksums[blockIdx.x] = woff + inc;   // block TOTAL (unscanned)
}

// ---------------- scan_add: add cross-block prefix; also emit cursor and dis ----------------

__global__ __launch_bounds__(256) void scan_add_kernel(int* __restrict__ rowptr,
                                                       int* __restrict__ cursor,
                                                       const unsigned* __restrict__ deg,
                                                       float* __restrict__ dis,
                                                       const int* __restrict__ blocksums,
                                                       int nb, int N, int E) {
    __shared__ int pre;
    const int t = threadIdx.x;
    const int i0 = blockIdx.x * 256;
    const int c0 = i0 / SCAN_BLK;
    if (t == 0) {
        int s = 0;
        for (int k = 0; k < c0; ++k) s += blocksums[k];
        pre = s;
    }
    __syncthreads();
    int i = i0 + t;
    if (i < N) {
        int v = rowptr[i] + pre;
        rowptr[i] = v;
        cursor[i] = v;
        unsigned d = deg[i];
        dis[i] = d ? 1.0f / sqrtf((float)d) : 0.0f;
    }
    if (i == 0) rowptr[N] = E;
}

// ---------------- counting-sort edges into CSR col array, row-range chunked ----------------
// chunk = blockIdx & 7 -> round-robins to one XCD (dispatch heuristic); each chunk's
// ~800 KB destination region stays L2-resident on one XCD so dirty lines fill fully.

__global__ __launch_bounds__(256) void scatter_edges_kernel(const int* __restrict__ rows,
                                                            const int* __restrict__ cols,
                                                            int* __restrict__ cursor,
                                                            int* __restrict__ colOut,
                                                            float chunk_scale, int E) {
    const int chunk = blockIdx.x & (NCHUNK - 1);
    const int eb = blockIdx.x >> 3;
    int e = eb * 256 + threadIdx.x;
    if (e >= E) return;
    int r = rows[e];
    int rc = (int)((float)r * chunk_scale);
    rc = rc > (NCHUNK - 1) ? (NCHUNK - 1) : rc;
    if (rc == chunk) {
        int p = atomicAdd(&cursor[r], 1);
        colOut[p] = cols[e];
    }
}

// ---------------- GEMM1: out[N][64] = (x[N][256] @ W[256][64] + b) * dis[r] ----------------
// 128-row tiles (782 blocks, ~3/CU) for latency hiding; per-thread 4 rows x 8 cols.

__global__ __launch_bounds__(256) void gemm1_kernel(const float* __restrict__ x,
                                                    const float* __restrict__ W,
                                                    const float* __restrict__ b,
                                                    const float* __restrict__ dis,
                                                    float* __restrict__ out, int N) {
    __shared__ float xs[32][132];
    __shared__ float ws[32][64];
    const int t = threadIdx.x;
    const int rb = blockIdx.x * 128;
    const int rg = t >> 3, cg = t & 7;
    const int r0 = rg * 4, c0 = cg * 8;
    float acc[4][8];
#pragma unroll
    for (int i = 0; i < 4; ++i)
#pragma unroll
        for (int j = 0; j < 8; ++j) acc[i][j] = 0.f;

    const float4* x4 = (const float4*)x;
    const int kk = (t & 7) * 4;
    const int rloc = t >> 3;

    for (int k0 = 0; k0 < FIN; k0 += 32) {
        __syncthreads();
        {
            const float4* w4 = (const float4*)(W + k0 * 64);
            float4* wl = (float4*)&ws[0][0];
            wl[t]       = w4[t];
            wl[t + 256] = w4[t + 256];
        }
#pragma unroll
        for (int p = 0; p < 4; ++p) {
            int r = rloc + p * 32;
            int gr = rb + r; if (gr >= N) gr = N - 1;
            float4 v = x4[gr * 64 + (k0 >> 2) + (t & 7)];
            xs[kk + 0][r] = v.x; xs[kk + 1][r] = v.y;
            xs[kk + 2][r] = v.z; xs[kk + 3][r] = v.w;
        }
        __syncthreads();
#pragma unroll
        for (int k = 0; k < 32; ++k) {
            float4 xa = *(const float4*)&xs[k][r0];
            float4 wa = *(const float4*)&ws[k][c0];
            float4 wb = *(const float4*)&ws[k][c0 + 4];
            float xr[4] = {xa.x, xa.y, xa.z, xa.w};
            float wr[8] = {wa.x, wa.y, wa.z, wa.w, wb.x, wb.y, wb.z, wb.w};
#pragma unroll
            for (int i = 0; i < 4; ++i)
#pragma unroll
                for (int j = 0; j < 8; ++j) acc[i][j] = fmaf(xr[i], wr[j], acc[i][j]);
        }
    }
    float bias[8];
#pragma unroll
    for (int j = 0; j < 8; ++j) bias[j] = b[c0 + j];
#pragma unroll
    for (int i = 0; i < 4; ++i) {
        int gr = rb + r0 + i;
        if (gr < N) {
            float d = dis[gr];
            float4 o0, o1;
            o0.x = (acc[i][0] + bias[0]) * d; o0.y = (acc[i][1] + bias[1]) * d;
            o0.z = (acc[i][2] + bias[2]) * d; o0.w = (acc[i][3] + bias[3]) * d;
            o1.x = (acc[i][4] + bias[4]) * d; o1.y = (acc[i][5] + bias[5]) * d;
            o1.z = (acc[i][6] + bias[6]) * d; o1.w = (acc[i][7] + bias[7]) * d;
            *(float4*)&out[gr * 64 + c0]     = o0;
            *(float4*)&out[gr * 64 + c0 + 4] = o1;
        }
    }
}

// ---------------- CSR gather aggregation: out[r] = scale(r) * sum over neighbors of h[c] ----------------
// one 64-lane wave per row, lane = feature; 8 independent loads in flight (ILP).
// dscale != nullptr -> multiply row result by dscale[r] (folds row-side dis for decode).

__global__ __launch_bounds__(256) void gather_agg_kernel(const int* __restrict__ rowptr,
                                                         const int* __restrict__ cols,
                                                         const float* __restrict__ h,
                                                         const float* __restrict__ dscale,
                                                         float* __restrict__ out, int N) {
    int r = blockIdx.x * 4 + (threadIdx.x >> 6);
    int lane = threadIdx.x & 63;
    if (r >= N) return;
    int s = rowptr[r], e = rowptr[r + 1];
    float acc0 = 0.f, acc1 = 0.f, acc2 = 0.f, acc3 = 0.f;
    float acc4 = 0.f, acc5 = 0.f, acc6 = 0.f, acc7 = 0.f;
    for (int base = s; base < e; base += 64) {
        int n = e - base; if (n > 64) n = 64;
        int idx = (lane < n) ? cols[base + lane] : 0;
        int j = 0;
        for (; j + 7 < n; j += 8) {
            int c0 = __shfl(idx, j, 64);
            int c1 = __shfl(idx, j + 1, 64);
            int c2 = __shfl(idx, j + 2, 64);
            int c3 = __shfl(idx, j + 3, 64);
            int c4 = __shfl(idx, j + 4, 64);
            int c5 = __shfl(idx, j + 5, 64);
            int c6 = __shfl(idx, j + 6, 64);
            int c7 = __shfl(idx, j + 7, 64);
            acc0 += h[(size_t)c0 * 64 + lane];
            acc1 += h[(size_t)c1 * 64 + lane];
            acc2 += h[(size_t)c2 * 64 + lane];
            acc3 += h[(size_t)c3 * 64 + lane];
            acc4 += h[(size_t)c4 * 64 + lane];
            acc5 += h[(size_t)c5 * 64 + lane];
            acc6 += h[(size_t)c6 * 64 + lane];
            acc7 += h[(size_t)c7 * 64 + lane];
        }
        for (; j + 3 < n; j += 4) {
            int c0 = __shfl(idx, j, 64);
            int c1 = __shfl(idx, j + 1, 64);
            int c2 = __shfl(idx, j + 2, 64);
            int c3 = __shfl(idx, j + 3, 64);
            acc0 += h[(size_t)c0 * 64 + lane];
            acc1 += h[(size_t)c1 * 64 + lane];
            acc2 += h[(size_t)c2 * 64 + lane];
            acc3 += h[(size_t)c3 * 64 + lane];
        }
        for (; j < n; ++j) {
            int c0 = __shfl(idx, j, 64);
            acc0 += h[(size_t)c0 * 64 + lane];
        }
    }
    float v = ((acc0 + acc1) + (acc2 + acc3)) + ((acc4 + acc5) + (acc6 + acc7));
    if (dscale) v *= dscale[r];
    out[(size_t)r * 64 + lane] = v;
}

// ---------------- GEMM2: out[N][64] = (relu(dis[r]*agg[r]) @ W[64][64] + b) * dis[r] ----------------

__global__ __launch_bounds__(256) void gemm2_kernel(const float* __restrict__ agg,
                                                    const float* __restrict__ dis,
                                                    const float* __restrict__ W,
                                                    const float* __restrict__ b,
                                                    float* __restrict__ out, int N) {
    __shared__ float xs[64][132];
    __shared__ float ws[64][64];
    const int t = threadIdx.x;
    const int rb = blockIdx.x * 128;
    {
        const float4* w4 = (const float4*)W;
        float4* wl = (float4*)&ws[0][0];
#pragma unroll
        for (int p = 0; p < 4; ++p) wl[p * 256 + t] = w4[p * 256 + t];
    }
    {
        const float4* a4 = (const float4*)agg;
        const int c4 = (t & 15) * 4;
        const int rloc = t >> 4;
#pragma unroll
        for (int p = 0; p < 8; ++p) {
            int r = rloc + p * 16;
            int gr = rb + r; if (gr >= N) gr = N - 1;
            float d = dis[gr];
            float4 v = a4[gr * 16 + (t & 15)];
            xs[c4 + 0][r] = fmaxf(v.x * d, 0.f);
            xs[c4 + 1][r] = fmaxf(v.y * d, 0.f);
            xs[c4 + 2][r] = fmaxf(v.z * d, 0.f);
            xs[c4 + 3][r] = fmaxf(v.w * d, 0.f);
        }
    }
    __syncthreads();
    const int rg = t >> 3, cg = t & 7;
    const int r0 = rg * 4, c0 = cg * 8;
    float acc[4][8];
#pragma unroll
    for (int i = 0; i < 4; ++i)
#pragma unroll
        for (int j = 0; j < 8; ++j) acc[i][j] = 0.f;
#pragma unroll 16
    for (int k = 0; k < 64; ++k) {
        float4 xa = *(const float4*)&xs[k][r0];
        float4 wa = *(const float4*)&ws[k][c0];
        float4 wb = *(const float4*)&ws[k][c0 + 4];
        float xr[4] = {xa.x, xa.y, xa.z, xa.w};
        float wr[8] = {wa.x, wa.y, wa.z, wa.w, wb.x, wb.y, wb.z, wb.w};
#pragma unroll
        for (int i = 0; i < 4; ++i)
#pragma unroll
            for (int j = 0; j < 8; ++j) acc[i][j] = fmaf(xr[i], wr[j], acc[i][j]);
    }
    float bias[8];
#pragma unroll
    for (int j = 0; j < 8; ++j) bias[j] = b[c0 + j];
#pragma unroll
    for (int i = 0; i < 4; ++i) {
        int gr = rb + r0 + i;
        if (gr < N) {
            float d = dis[gr];
            float4 o0, o1;
            o0.x = (acc[i][0] + bias[0]) * d; o0.y = (acc[i][1] + bias[1]) * d;
            o0.z = (acc[i][2] + bias[2]) * d; o0.w = (acc[i][3] + bias[3]) * d;
            o1.x = (acc[i][4] + bias[4]) * d; o1.y = (acc[i][5] + bias[5]) * d;
            o1.z = (acc[i][6] + bias[6]) * d; o1.w = (acc[i][7] + bias[7]) * d;
            *(float4*)&out[gr * 64 + c0]     = o0;
            *(float4*)&out[gr * 64 + c0 + 4] = o1;
        }
    }
}

// ---------------- decode: out[e] = dot64(z[a], z[b]); z carries ALL dis factors ----------------
// 16 lanes per edge, 4 edges per group in flight (8 independent 256B loads).

__global__ __launch_bounds__(256) void decode_kernel(const int* __restrict__ pe,
                                                     const int* __restrict__ ne,
                                                     const float* __restrict__ z,
                                                     float* __restrict__ out, int Ep, int En) {
    const int t = threadIdx.x;
    const int grp = t >> 4;      // 0..15
    const int l16 = t & 15;
    const int Etot = Ep + En;
    const int base = blockIdx.x * 64 + grp;
    const float4* z4 = (const float4*)z;

    int a[4], b[4];
    bool v[4];
#pragma unroll
    for (int q = 0; q < 4; ++q) {
        int e = base + q * 16;
        v[q] = e < Etot;
        a[q] = 0; b[q] = 0;
        if (v[q]) {
            if (e < Ep) { a[q] = pe[e]; b[q] = pe[Ep + e]; }
            else        { int j = e - Ep; a[q] = ne[j]; b[q] = ne[En + j]; }
        }
    }
    float4 va[4], vb[4];
#pragma unroll
    for (int q = 0; q < 4; ++q) {
        va[q] = z4[(size_t)a[q] * 16 + l16];
        vb[q] = z4[(size_t)b[q] * 16 + l16];
    }
    float s[4];
#pragma unroll
    for (int q = 0; q < 4; ++q) {
        float p = va[q].x * vb[q].x + va[q].y * vb[q].y
                + va[q].z * vb[q].z + va[q].w * vb[q].w;
        p += __shfl_xor(p, 8);
        p += __shfl_xor(p, 4);
        p += __shfl_xor(p, 2);
        p += __shfl_xor(p, 1);
        s[q] = p;
    }
#pragma unroll
    for (int q = 0; q < 4; ++q) {
        if (v[q] && l16 == 0) {
            out[base + q * 16] = s[q];
        }
    }
}

// ---------------- launch ----------------

extern "C" void kernel_launch(void* const* d_in, const int* in_sizes, int n_in,
                              void* d_out, int out_size, void* d_ws, size_t ws_size,
                              hipStream_t stream) {
    const float* x  = (const float*)d_in[0];
    const int*   pe = (const int*)d_in[1];
    const int*   ne = (const int*)d_in[2];
    const float* W1 = (const float*)d_in[3];
    const float* b1 = (const float*)d_in[4];
    const float* W2 = (const float*)d_in[5];
    const float* b2 = (const float*)d_in[6];
    float* outp = (float*)d_out;

    const int N  = in_sizes[0] / FIN;
    const int Ep = in_sizes[1] / 2;
    const int En = in_sizes[2] / 2;

    char* w = (char*)d_ws;
    size_t off = 0;
    auto alloc = [&](size_t bytes) {
        void* p = w + off;
        off = (off + bytes + 255) & ~(size_t)255;
        return p;
    };
    unsigned* deg   = (unsigned*)alloc((size_t)N * 4);
    float* dis      = (float*)alloc((size_t)N * 4);
    int* rowptr     = (int*)alloc((size_t)(N + 1) * 4);
    int* cursor     = (int*)alloc((size_t)N * 4);
    int* blocksums  = (int*)alloc(((size_t)N / SCAN_BLK + 2) * 4);
    int* colsorted  = (int*)alloc((size_t)Ep * 4);
    float* A        = (float*)alloc((size_t)N * 64 * 4);   // h, then h2 (col-side dis folded)
    float* B        = (float*)alloc((size_t)N * 64 * 4);   // agg1, then zfull

    const int nscan = (N + SCAN_BLK - 1) / SCAN_BLK;
    const int nEdgeBlocks = (Ep + 255) / 256;

    hipMemsetAsync(deg, 0, (size_t)N * 4, stream);

    // CSR build (pos edges)
    deg_kernel<<<nEdgeBlocks, 256, 0, stream>>>(pe, deg, Ep);
    scan_block_kernel<<<nscan, 256, 0, stream>>>(deg, rowptr, blocksums, N);
    scan_add_kernel<<<(N + 255) / 256, 256, 0, stream>>>(rowptr, cursor, deg, dis,
                                                         blocksums, nscan, N, Ep);
    scatter_edges_kernel<<<nEdgeBlocks * NCHUNK, 256, 0, stream>>>(
        pe, pe + Ep, cursor, colsorted, (float)NCHUNK / (float)N, Ep);
    // layer 1
    gemm1_kernel<<<(N + 127) / 128, 256, 0, stream>>>(x, W1, b1, dis, A, N);
    gather_agg_kernel<<<(N + 3) / 4, 256, 0, stream>>>(rowptr, colsorted, A, nullptr, B, N);
    // layer 2
    gemm2_kernel<<<(N + 127) / 128, 256, 0, stream>>>(B, dis, W2, b2, A, N);
    gather_agg_kernel<<<(N + 3) / 4, 256, 0, stream>>>(rowptr, colsorted, A, dis, B, N);
    // decode (z = B carries all dis factors)
    decode_kernel<<<(Ep + En + 63) / 64, 256, 0, stream>>>(pe, ne, B, outp, Ep, En);
}

// Round 8
// 650.040 us; speedup vs baseline: 1.3909x; 1.0080x over previous
//
#include <hip/hip_runtime.h>

#define FIN 256
#define FH  64
#define SCAN_BLK 1024
#define NCHUNK 8

// ---------------- degree ----------------

__global__ __launch_bounds__(256) void deg_kernel(const int* __restrict__ rows,
                                                  unsigned* __restrict__ deg, int E) {
    int e = blockIdx.x * 256 + threadIdx.x;
    if (e < E) atomicAdd(&deg[rows[e]], 1u);
}

// ---------------- scan: per-block scan of deg -> rowptr (block-local) + block totals ----------------

__global__ __launch_bounds__(256) void scan_block_kernel(const unsigned* __restrict__ deg,
                                                         int* __restrict__ rowptr,
                                                         int* __restrict__ blocksums, int N) {
    __shared__ int wsum[4];
    const int t = threadIdx.x;
    const int base = blockIdx.x * SCAN_BLK + t * 4;
    int d0 = 0, d1 = 0, d2 = 0, d3 = 0;
    if (base + 0 < N) d0 = (int)deg[base + 0];
    if (base + 1 < N) d1 = (int)deg[base + 1];
    if (base + 2 < N) d2 = (int)deg[base + 2];
    if (base + 3 < N) d3 = (int)deg[base + 3];
    const int tot = d0 + d1 + d2 + d3;
    const int lane = t & 63, wv = t >> 6;
    int inc = tot;
#pragma unroll
    for (int off = 1; off < 64; off <<= 1) {
        int v = __shfl_up(inc, off, 64);
        if (lane >= off) inc += v;
    }
    if (lane == 63) wsum[wv] = inc;
    __syncthreads();
    int woff = 0;
    for (int w = 0; w < wv; ++w) woff += wsum[w];
    const int ex = woff + inc - tot;   // exclusive prefix of this thread within block
    if (base + 0 < N) rowptr[base + 0] = ex;
    if (base + 1 < N) rowptr[base + 1] = ex + d0;
    if (base + 2 < N) rowptr[base + 2] = ex + d0 + d1;
    if (base + 3 < N) rowptr[base + 3] = ex + d0 + d1 + d2;
    if (t == 255) blocksums[blockIdx.x] = woff + inc;   // block TOTAL (unscanned)
}

// ---------------- scan_add: add cross-block prefix; also emit cursor and dis ----------------

__global__ __launch_bounds__(256) void scan_add_kernel(int* __restrict__ rowptr,
                                                       int* __restrict__ cursor,
                                                       const unsigned* __restrict__ deg,
                                                       float* __restrict__ dis,
                                                       const int* __restrict__ blocksums,
                                                       int nb, int N, int E) {
    __shared__ int pre;
    const int t = threadIdx.x;
    const int i0 = blockIdx.x * 256;
    const int c0 = i0 / SCAN_BLK;
    if (t == 0) {
        int s = 0;
        for (int k = 0; k < c0; ++k) s += blocksums[k];
        pre = s;
    }
    __syncthreads();
    int i = i0 + t;
    if (i < N) {
        int v = rowptr[i] + pre;
        rowptr[i] = v;
        cursor[i] = v;
        unsigned d = deg[i];
        dis[i] = d ? 1.0f / sqrtf((float)d) : 0.0f;
    }
    if (i == 0) rowptr[N] = E;
}

// ---------------- counting-sort edges into CSR col array, row-range chunked ----------------
// chunk = blockIdx & 7 -> round-robins to one XCD; destination region per chunk stays
// L2-resident so dirty lines fill fully. Also records inv[e] = CSR position of edge e
// (sequential write in e) so pos-decode results can be permuted back cheaply.

__global__ __launch_bounds__(256) void scatter_edges_kernel(const int* __restrict__ rows,
                                                            const int* __restrict__ cols,
                                                            int* __restrict__ cursor,
                                                            int* __restrict__ colOut,
                                                            int* __restrict__ inv,
                                                            float chunk_scale, int E) {
    const int chunk = blockIdx.x & (NCHUNK - 1);
    const int eb = blockIdx.x >> 3;
    int e = eb * 256 + threadIdx.x;
    if (e >= E) return;
    int r = rows[e];
    int rc = (int)((float)r * chunk_scale);
    rc = rc > (NCHUNK - 1) ? (NCHUNK - 1) : rc;
    if (rc == chunk) {
        int p = atomicAdd(&cursor[r], 1);
        colOut[p] = cols[e];
        inv[e] = p;
    }
}

// ---------------- GEMM1: out[N][64] = (x[N][256] @ W[256][64] + b) * dis[r] ----------------

__global__ __launch_bounds__(256) void gemm1_kernel(const float* __restrict__ x,
                                                    const float* __restrict__ W,
                                                    const float* __restrict__ b,
                                                    const float* __restrict__ dis,
                                                    float* __restrict__ out, int N) {
    __shared__ float xs[32][132];
    __shared__ float ws[32][64];
    const int t = threadIdx.x;
    const int rb = blockIdx.x * 128;
    const int rg = t >> 3, cg = t & 7;
    const int r0 = rg * 4, c0 = cg * 8;
    float acc[4][8];
#pragma unroll
    for (int i = 0; i < 4; ++i)
#pragma unroll
        for (int j = 0; j < 8; ++j) acc[i][j] = 0.f;

    const float4* x4 = (const float4*)x;
    const int kk = (t & 7) * 4;
    const int rloc = t >> 3;

    for (int k0 = 0; k0 < FIN; k0 += 32) {
        __syncthreads();
        {
            const float4* w4 = (const float4*)(W + k0 * 64);
            float4* wl = (float4*)&ws[0][0];
            wl[t]       = w4[t];
            wl[t + 256] = w4[t + 256];
        }
#pragma unroll
        for (int p = 0; p < 4; ++p) {
            int r = rloc + p * 32;
            int gr = rb + r; if (gr >= N) gr = N - 1;
            float4 v = x4[gr * 64 + (k0 >> 2) + (t & 7)];
            xs[kk + 0][r] = v.x; xs[kk + 1][r] = v.y;
            xs[kk + 2][r] = v.z; xs[kk + 3][r] = v.w;
        }
        __syncthreads();
#pragma unroll
        for (int k = 0; k < 32; ++k) {
            float4 xa = *(const float4*)&xs[k][r0];
            float4 wa = *(const float4*)&ws[k][c0];
            float4 wb = *(const float4*)&ws[k][c0 + 4];
            float xr[4] = {xa.x, xa.y, xa.z, xa.w};
            float wr[8] = {wa.x, wa.y, wa.z, wa.w, wb.x, wb.y, wb.z, wb.w};
#pragma unroll
            for (int i = 0; i < 4; ++i)
#pragma unroll
                for (int j = 0; j < 8; ++j) acc[i][j] = fmaf(xr[i], wr[j], acc[i][j]);
        }
    }
    float bias[8];
#pragma unroll
    for (int j = 0; j < 8; ++j) bias[j] = b[c0 + j];
#pragma unroll
    for (int i = 0; i < 4; ++i) {
        int gr = rb + r0 + i;
        if (gr < N) {
            float d = dis[gr];
            float4 o0, o1;
            o0.x = (acc[i][0] + bias[0]) * d; o0.y = (acc[i][1] + bias[1]) * d;
            o0.z = (acc[i][2] + bias[2]) * d; o0.w = (acc[i][3] + bias[3]) * d;
            o1.x = (acc[i][4] + bias[4]) * d; o1.y = (acc[i][5] + bias[5]) * d;
            o1.z = (acc[i][6] + bias[6]) * d; o1.w = (acc[i][7] + bias[7]) * d;
            *(float4*)&out[gr * 64 + c0]     = o0;
            *(float4*)&out[gr * 64 + c0 + 4] = o1;
        }
    }
}

// ---------------- CSR gather aggregation ----------------

__global__ __launch_bounds__(256) void gather_agg_kernel(const int* __restrict__ rowptr,
                                                         const int* __restrict__ cols,
                                                         const float* __restrict__ h,
                                                         const float* __restrict__ dscale,
                                                         float* __restrict__ out, int N) {
    int r = blockIdx.x * 4 + (threadIdx.x >> 6);
    int lane = threadIdx.x & 63;
    if (r >= N) return;
    int s = rowptr[r], e = rowptr[r + 1];
    float acc0 = 0.f, acc1 = 0.f, acc2 = 0.f, acc3 = 0.f;
    float acc4 = 0.f, acc5 = 0.f, acc6 = 0.f, acc7 = 0.f;
    for (int base = s; base < e; base += 64) {
        int n = e - base; if (n > 64) n = 64;
        int idx = (lane < n) ? cols[base + lane] : 0;
        int j = 0;
        for (; j + 7 < n; j += 8) {
            int c0 = __shfl(idx, j, 64);
            int c1 = __shfl(idx, j + 1, 64);
            int c2 = __shfl(idx, j + 2, 64);
            int c3 = __shfl(idx, j + 3, 64);
            int c4 = __shfl(idx, j + 4, 64);
            int c5 = __shfl(idx, j + 5, 64);
            int c6 = __shfl(idx, j + 6, 64);
            int c7 = __shfl(idx, j + 7, 64);
            acc0 += h[(size_t)c0 * 64 + lane];
            acc1 += h[(size_t)c1 * 64 + lane];
            acc2 += h[(size_t)c2 * 64 + lane];
            acc3 += h[(size_t)c3 * 64 + lane];
            acc4 += h[(size_t)c4 * 64 + lane];
            acc5 += h[(size_t)c5 * 64 + lane];
            acc6 += h[(size_t)c6 * 64 + lane];
            acc7 += h[(size_t)c7 * 64 + lane];
        }
        for (; j + 3 < n; j += 4) {
            int c0 = __shfl(idx, j, 64);
            int c1 = __shfl(idx, j + 1, 64);
            int c2 = __shfl(idx, j + 2, 64);
            int c3 = __shfl(idx, j + 3, 64);
            acc0 += h[(size_t)c0 * 64 + lane];
            acc1 += h[(size_t)c1 * 64 + lane];
            acc2 += h[(size_t)c2 * 64 + lane];
            acc3 += h[(size_t)c3 * 64 + lane];
        }
        for (; j < n; ++j) {
            int c0 = __shfl(idx, j, 64);
            acc0 += h[(size_t)c0 * 64 + lane];
        }
    }
    float v = ((acc0 + acc1) + (acc2 + acc3)) + ((acc4 + acc5) + (acc6 + acc7));
    if (dscale) v *= dscale[r];
    out[(size_t)r * 64 + lane] = v;
}

// ---------------- GEMM2 ----------------

__global__ __launch_bounds__(256) void gemm2_kernel(const float* __restrict__ agg,
                                                    const float* __restrict__ dis,
                                                    const float* __restrict__ W,
                                                    const float* __restrict__ b,
                                                    float* __restrict__ out, int N) {
    __shared__ float xs[64][132];
    __shared__ float ws[64][64];
    const int t = threadIdx.x;
    const int rb = blockIdx.x * 128;
    {
        const float4* w4 = (const float4*)W;
        float4* wl = (float4*)&ws[0][0];
#pragma unroll
        for (int p = 0; p < 4; ++p) wl[p * 256 + t] = w4[p * 256 + t];
    }
    {
        const float4* a4 = (const float4*)agg;
        const int c4 = (t & 15) * 4;
        const int rloc = t >> 4;
#pragma unroll
        for (int p = 0; p < 8; ++p) {
            int r = rloc + p * 16;
            int gr = rb + r; if (gr >= N) gr = N - 1;
            float d = dis[gr];
            float4 v = a4[gr * 16 + (t & 15)];
            xs[c4 + 0][r] = fmaxf(v.x * d, 0.f);
            xs[c4 + 1][r] = fmaxf(v.y * d, 0.f);
            xs[c4 + 2][r] = fmaxf(v.z * d, 0.f);
            xs[c4 + 3][r] = fmaxf(v.w * d, 0.f);
        }
    }
    __syncthreads();
    const int rg = t >> 3, cg = t & 7;
    const int r0 = rg * 4, c0 = cg * 8;
    float acc[4][8];
#pragma unroll
    for (int i = 0; i < 4; ++i)
#pragma unroll
        for (int j = 0; j < 8; ++j) acc[i][j] = 0.f;
#pragma unroll 16
    for (int k = 0; k < 64; ++k) {
        float4 xa = *(const float4*)&xs[k][r0];
        float4 wa = *(const float4*)&ws[k][c0];
        float4 wb = *(const float4*)&ws[k][c0 + 4];
        float xr[4] = {xa.x, xa.y, xa.z, xa.w};
        float wr[8] = {wa.x, wa.y, wa.z, wa.w, wb.x, wb.y, wb.z, wb.w};
#pragma unroll
        for (int i = 0; i < 4; ++i)
#pragma unroll
            for (int j = 0; j < 8; ++j) acc[i][j] = fmaf(xr[i], wr[j], acc[i][j]);
    }
    float bias[8];
#pragma unroll
    for (int j = 0; j < 8; ++j) bias[j] = b[c0 + j];
#pragma unroll
    for (int i = 0; i < 4; ++i) {
        int gr = rb + r0 + i;
        if (gr < N) {
            float d = dis[gr];
            float4 o0, o1;
            o0.x = (acc[i][0] + bias[0]) * d; o0.y = (acc[i][1] + bias[1]) * d;
            o0.z = (acc[i][2] + bias[2]) * d; o0.w = (acc[i][3] + bias[3]) * d;
            o1.x = (acc[i][4] + bias[4]) * d; o1.y = (acc[i][5] + bias[5]) * d;
            o1.z = (acc[i][6] + bias[6]) * d; o1.w = (acc[i][7] + bias[7]) * d;
            *(float4*)&out[gr * 64 + c0]     = o0;
            *(float4*)&out[gr * 64 + c0 + 4] = o1;
        }
    }
}

// ---------------- pos decode via CSR: P[p] = dot64(z[a], z[colsorted[p]]) ----------------
// wave per row a; z[a] in registers (replicated over four 16-lane groups);
// 4 neighbors/iter; results written SEQUENTIALLY in CSR order.

__global__ __launch_bounds__(256) void decode_csr_kernel(const int* __restrict__ rowptr,
                                                         const int* __restrict__ cols,
                                                         const float* __restrict__ z,
                                                         float* __restrict__ P, int N) {
    int r = blockIdx.x * 4 + (threadIdx.x >> 6);
    int lane = threadIdx.x & 63;
    if (r >= N) return;
    int s = rowptr[r], e = rowptr[r + 1];
    if (s == e) return;
    const int l16 = lane & 15;
    const int grp = lane >> 4;
    const float4* z4 = (const float4*)z;
    const float4 zr = z4[(size_t)r * 16 + l16];
#pragma unroll 2
    for (int j = s; j < e; j += 4) {
        int jj = j + grp;
        bool act = jj < e;
        int c = cols[act ? jj : s];
        float4 vb = z4[(size_t)c * 16 + l16];
        float p = zr.x * vb.x + zr.y * vb.y + zr.z * vb.z + zr.w * vb.w;
        p += __shfl_xor(p, 8);
        p += __shfl_xor(p, 4);
        p += __shfl_xor(p, 2);
        p += __shfl_xor(p, 1);
        if (act && l16 == 0) P[jj] = p;
    }
}

// ---------------- permute: out[e] = P[inv[e]] (seq read/write, gather from L2-resident P) --------

__global__ __launch_bounds__(256) void permute_kernel(const float* __restrict__ P,
                                                      const int* __restrict__ inv,
                                                      float* __restrict__ out, int E) {
    int e = blockIdx.x * 256 + threadIdx.x;
    if (e < E) out[e] = P[inv[e]];
}

// ---------------- neg decode: out[Ep+j] = dot64(z[a], z[b]) ----------------
// 16 lanes per edge, 4 edges per group in flight (8 independent 256B loads).

__global__ __launch_bounds__(256) void decode_neg_kernel(const int* __restrict__ ne,
                                                         const float* __restrict__ z,
                                                         float* __restrict__ out, int En) {
    const int t = threadIdx.x;
    const int grp = t >> 4;      // 0..15
    const int l16 = t & 15;
    const int base = blockIdx.x * 64 + grp;
    const float4* z4 = (const float4*)z;

    int a[4], b[4];
    bool v[4];
#pragma unroll
    for (int q = 0; q < 4; ++q) {
        int e = base + q * 16;
        v[q] = e < En;
        a[q] = 0; b[q] = 0;
        if (v[q]) { a[q] = ne[e]; b[q] = ne[En + e]; }
    }
    float4 va[4], vb[4];
#pragma unroll
    for (int q = 0; q < 4; ++q) {
        va[q] = z4[(size_t)a[q] * 16 + l16];
        vb[q] = z4[(size_t)b[q] * 16 + l16];
    }
#pragma unroll
    for (int q = 0; q < 4; ++q) {
        float p = va[q].x * vb[q].x + va[q].y * vb[q].y
                + va[q].z * vb[q].z + va[q].w * vb[q].w;
        p += __shfl_xor(p, 8);
        p += __shfl_xor(p, 4);
        p += __shfl_xor(p, 2);
        p += __shfl_xor(p, 1);
        if (v[q] && l16 == 0) out[base + q * 16] = p;
    }
}

// ---------------- launch ----------------

extern "C" void kernel_launch(void* const* d_in, const int* in_sizes, int n_in,
                              void* d_out, int out_size, void* d_ws, size_t ws_size,
                              hipStream_t stream) {
    const float* x  = (const float*)d_in[0];
    const int*   pe = (const int*)d_in[1];
    const int*   ne = (const int*)d_in[2];
    const float* W1 = (const float*)d_in[3];
    const float* b1 = (const float*)d_in[4];
    const float* W2 = (const float*)d_in[5];
    const float* b2 = (const float*)d_in[6];
    float* outp = (float*)d_out;

    const int N  = in_sizes[0] / FIN;
    const int Ep = in_sizes[1] / 2;
    const int En = in_sizes[2] / 2;

    char* w = (char*)d_ws;
    size_t off = 0;
    auto alloc = [&](size_t bytes) {
        void* p = w + off;
        off = (off + bytes + 255) & ~(size_t)255;
        return p;
    };
    unsigned* deg   = (unsigned*)alloc((size_t)N * 4);
    float* dis      = (float*)alloc((size_t)N * 4);
    int* rowptr     = (int*)alloc((size_t)(N + 1) * 4);
    int* cursor     = (int*)alloc((size_t)N * 4);
    int* blocksums  = (int*)alloc(((size_t)N / SCAN_BLK + 2) * 4);
    int* colsorted  = (int*)alloc((size_t)Ep * 4);
    int* inv        = (int*)alloc((size_t)Ep * 4);
    float* A        = (float*)alloc((size_t)N * 64 * 4);   // h, then h2, then P (pos decode buf)
    float* B        = (float*)alloc((size_t)N * 64 * 4);   // agg1, then zfull

    const int nscan = (N + SCAN_BLK - 1) / SCAN_BLK;
    const int nEdgeBlocks = (Ep + 255) / 256;

    hipMemsetAsync(deg, 0, (size_t)N * 4, stream);

    // CSR build (pos edges)
    deg_kernel<<<nEdgeBlocks, 256, 0, stream>>>(pe, deg, Ep);
    scan_block_kernel<<<nscan, 256, 0, stream>>>(deg, rowptr, blocksums, N);
    scan_add_kernel<<<(N + 255) / 256, 256, 0, stream>>>(rowptr, cursor, deg, dis,
                                                         blocksums, nscan, N, Ep);
    scatter_edges_kernel<<<nEdgeBlocks * NCHUNK, 256, 0, stream>>>(
        pe, pe + Ep, cursor, colsorted, inv, (float)NCHUNK / (float)N, Ep);
    // layer 1
    gemm1_kernel<<<(N + 127) / 128, 256, 0, stream>>>(x, W1, b1, dis, A, N);
    gather_agg_kernel<<<(N + 3) / 4, 256, 0, stream>>>(rowptr, colsorted, A, nullptr, B, N);
    // layer 2
    gemm2_kernel<<<(N + 127) / 128, 256, 0, stream>>>(B, dis, W2, b2, A, N);
    gather_agg_kernel<<<(N + 3) / 4, 256, 0, stream>>>(rowptr, colsorted, A, dis, B, N);
    // decode: pos via CSR (z[a] in regs, sequential P write) + permute back; neg via gather
    float* P = A;   // h2 dead after gather2
    decode_csr_kernel<<<(N + 3) / 4, 256, 0, stream>>>(rowptr, colsorted, B, P, N);
    decode_neg_kernel<<<(En + 63) / 64, 256, 0, stream>>>(ne, B, outp + Ep, En);
    permute_kernel<<<(Ep + 255) / 256, 256, 0, stream>>>(P, inv, outp, Ep);
}